// Round 5
// baseline (2029.345 us; speedup 1.0000x reference)
//
#include <hip/hip_runtime.h>
#include <cstdint>
#include <cstddef>

#define IN_DIM 512
#define HID 2048
#define TOPK 50
#define MARGIN 4e-5f

typedef __attribute__((ext_vector_type(8))) short short8;
typedef __attribute__((ext_vector_type(4))) float f32x4;

__device__ __forceinline__ unsigned short f2bf(float f) {
  unsigned b = __float_as_uint(f);
  b += 0x7fffu + ((b >> 16) & 1u);          // round-to-nearest-even
  return (unsigned short)(b >> 16);
}
__device__ __forceinline__ float bf2f(unsigned short u) {
  return __uint_as_float(((unsigned)u) << 16);
}
__device__ __forceinline__ unsigned f2code(float f) {
  const unsigned b = __float_as_uint(f);
  return (b & 0x80000000u) ? ~b : (b | 0x80000000u);   // order-preserving
}
__device__ __forceinline__ float code2f(unsigned t) {
  return __uint_as_float((t & 0x80000000u) ? (t & 0x7fffffffu) : ~t);
}
__device__ __forceinline__ void dma16(const void* g, void* l) {
  __builtin_amdgcn_global_load_lds(
      (const __attribute__((address_space(1))) void*)g,
      (__attribute__((address_space(3))) void*)l, 16, 0, 0);
}
__device__ __forceinline__ unsigned wave_max_u(unsigned m) {
#pragma unroll
  for (int s = 32; s > 0; s >>= 1) {
    const unsigned o = __shfl_xor(m, s, 64);
    m = o > m ? o : m;
  }
  return m;
}

// ---------------------------------------------------------------------------
// K0: transpose W_dec (512 x 2048) -> W_dec_T (2048 x 512)
// ---------------------------------------------------------------------------
__global__ __launch_bounds__(256) void transpose_wdec_kernel(
    const float* __restrict__ Wd, float* __restrict__ WdT)
{
  __shared__ float tile[32][33];
  const int bx = blockIdx.x & 63;
  const int by = blockIdx.x >> 6;
  const int tx = threadIdx.x & 31;
  const int ty = threadIdx.x >> 5;
#pragma unroll
  for (int i = 0; i < 4; ++i)
    tile[ty + i * 8][tx] = Wd[(size_t)(by * 32 + ty + i * 8) * HID + bx * 32 + tx];
  __syncthreads();
#pragma unroll
  for (int i = 0; i < 4; ++i)
    WdT[(size_t)(bx * 32 + ty + i * 8) * IN_DIM + by * 32 + tx] = tile[tx][ty + i * 8];
}

// ---------------------------------------------------------------------------
// K1a: split W_enc (2048x512 fp32) -> WeHi, WeLo (bf16 as ushort)
// ---------------------------------------------------------------------------
__global__ __launch_bounds__(256) void split_we_kernel(
    const float* __restrict__ We, unsigned short* __restrict__ wh,
    unsigned short* __restrict__ wl)
{
  const int i4 = blockIdx.x * 256 + threadIdx.x;   // HID*IN_DIM/4 total
  const float4 v = ((const float4*)We)[i4];
  ushort4 h, l;
  h.x = f2bf(v.x); l.x = f2bf(v.x - bf2f(h.x));
  h.y = f2bf(v.y); l.y = f2bf(v.y - bf2f(h.y));
  h.z = f2bf(v.z); l.z = f2bf(v.z - bf2f(h.z));
  h.w = f2bf(v.w); l.w = f2bf(v.w - bf2f(h.w));
  ((ushort4*)wh)[i4] = h;
  ((ushort4*)wl)[i4] = l;
}

// ---------------------------------------------------------------------------
// K1b: xc = x - (b_dec + pre_bias); split -> xcHi, xcLo (stored in recon area)
// ---------------------------------------------------------------------------
__global__ __launch_bounds__(256) void split_x_kernel(
    const float* __restrict__ x, const float* __restrict__ bd,
    const float* __restrict__ pb, unsigned short* __restrict__ xh,
    unsigned short* __restrict__ xl)
{
  const int i4 = blockIdx.x * 256 + threadIdx.x;   // M*IN_DIM/4 total
  const int k4 = (i4 & 127) * 4;
  const float4 v = ((const float4*)x)[i4];
  const float4 b = *(const float4*)(bd + k4);
  const float4 p = *(const float4*)(pb + k4);
  float c0 = v.x - (b.x + p.x);
  float c1 = v.y - (b.y + p.y);
  float c2 = v.z - (b.z + p.z);
  float c3 = v.w - (b.w + p.w);
  ushort4 h, l;
  h.x = f2bf(c0); l.x = f2bf(c0 - bf2f(h.x));
  h.y = f2bf(c1); l.y = f2bf(c1 - bf2f(h.y));
  h.z = f2bf(c2); l.z = f2bf(c2 - bf2f(h.z));
  h.w = f2bf(c3); l.w = f2bf(c3 - bf2f(h.w));
  ((ushort4*)xh)[i4] = h;
  ((ushort4*)xl)[i4] = l;
}

// ---------------------------------------------------------------------------
// K2 (ROUND-4 REWRITE): fragment-level fused bf16x3 GEMM.
// z = xc @ We^T + be with xc ~ xh+xl, We ~ wh+wl, computing per K32-tile the
// three limb products with REGISTER REUSE:
//   ph_a: acc += ah x bh   (reads 8 ah + 4 bh from LDS; stages Ah,Bh(t+1))
//   ph_b: acc += ah x bl   (reads 4 bl; ah reused in regs; stages Al(t+1))
//   ph_c: acc += al x bh   (reads 8 al; bh reused in regs; stages Bl(t+1))
// vs the K'=1536 concatenation this cuts LDS reads 33% (0.375 -> 0.25
// b128/MFMA), staging 33% (1.54 -> 1.02 MB/block), and phases 96 -> 48
// (32 MFMA each). LDS-read floor drops from ~110% to ~62% of the MFMA
// floor -> MFMA becomes the critical pipe.
//
// LDS: 4 arrays (Ah,Al,Bh,Bl) x double-buffer x [256x32] bf16 = 128 KB.
// 8 waves (2M x 4N), wave tile 128x64, acc 8x4 f32x4.
//
// vmcnt LEDGER (per-wave instruction counts; each STAGE = 2 dma):
//   issue stream per tile t: ph_a{Ah,Bh(t+1)}=4, ph_b{Al(t+1)}=2,
//   ph_c{Bl(t+1)}=2.
//   - t.ph_a reads Ah,Bh(t): staged t-1.ph_a. Guarded by vmcnt(4) at end of
//     t-1.ph_c: newest 4 = {Al(t),Bl(t)} -> Ah,Bh(t) complete.
//   - t.ph_b reads Bl(t): staged t-1.ph_c. Guarded by vmcnt(4) at end of
//     t.ph_a: newest 4 = t.ph_a's own stages -> Bl(t) complete.
//   - t.ph_c reads Al(t): staged t-1.ph_b, older than t.ph_a's 4 -> complete
//     by the same wait. No wait needed at end of ph_b.
//   vmcnt is per-wave; the s_barrier AFTER each wait makes every wave's own
//   slice guarantee collective. Prologue stages tile 0 (8 instr) then
//   vmcnt(4)+barrier (Ah,Bh done; Al,Bl covered by end-of-ph_a wait).
//   Tail (t=15) stages tile 0 (garbage, never read) to keep counts valid.
// Every buffer is staged >= 3 phases (~750 ns) before first read >> HBM
// latency. WAR on LDS: re-staging a parity buffer happens >= 3 barriers
// after its last reader phase.
// ---------------------------------------------------------------------------
__device__ __forceinline__ short8 ldfrag(const unsigned short* h, int row, int fq3) {
  const int qs = fq3 ^ ((row >> 1) & 3);
  return *(const short8*)(h + row * 32 + qs * 8);
}

#define MFMA32(AF, BF)                                                            \
  _Pragma("unroll")                                                               \
  for (int mt = 0; mt < 8; ++mt)                                                  \
    _Pragma("unroll")                                                             \
    for (int nt = 0; nt < 4; ++nt)                                                \
      acc[mt][nt] = __builtin_amdgcn_mfma_f32_16x16x32_bf16(AF[mt], BF[nt], acc[mt][nt], 0, 0, 0);

#define TILE_BODY(P, Q, KT1) do {                                                 \
  /* ---- ph_a: ah x bh ---- */                                                   \
  _Pragma("unroll")                                                               \
  for (int mt = 0; mt < 8; ++mt) ah[mt] = ldfrag(sAh[P], wm * 128 + mt * 16 + fr, fq3); \
  _Pragma("unroll")                                                               \
  for (int nt = 0; nt < 4; ++nt) bh[nt] = ldfrag(sBh[P], wn * 64 + nt * 16 + fr, fq3);  \
  dma16(xh + aoff0 + (KT1) * 32, &sAh[Q][wv * 512]);                              \
  dma16(xh + aoff1 + (KT1) * 32, &sAh[Q][wv * 512 + 4096]);                       \
  dma16(wh + boff0 + (KT1) * 32, &sBh[Q][wv * 512]);                              \
  dma16(wh + boff1 + (KT1) * 32, &sBh[Q][wv * 512 + 4096]);                       \
  __builtin_amdgcn_s_barrier();                                                   \
  __builtin_amdgcn_s_setprio(1);                                                  \
  MFMA32(ah, bh)                                                                  \
  __builtin_amdgcn_s_setprio(0);                                                  \
  asm volatile("s_waitcnt vmcnt(4)" ::: "memory");                                \
  __builtin_amdgcn_s_barrier();                                                   \
  /* ---- ph_b: ah x bl (ah reused) ---- */                                       \
  _Pragma("unroll")                                                               \
  for (int nt = 0; nt < 4; ++nt) bl[nt] = ldfrag(sBl[P], wn * 64 + nt * 16 + fr, fq3);  \
  dma16(xl + aoff0 + (KT1) * 32, &sAl[Q][wv * 512]);                              \
  dma16(xl + aoff1 + (KT1) * 32, &sAl[Q][wv * 512 + 4096]);                       \
  __builtin_amdgcn_s_barrier();                                                   \
  __builtin_amdgcn_s_setprio(1);                                                  \
  MFMA32(ah, bl)                                                                  \
  __builtin_amdgcn_s_setprio(0);                                                  \
  __builtin_amdgcn_s_barrier();                                                   \
  /* ---- ph_c: al x bh (bh reused) ---- */                                       \
  _Pragma("unroll")                                                               \
  for (int mt = 0; mt < 8; ++mt) al[mt] = ldfrag(sAl[P], wm * 128 + mt * 16 + fr, fq3); \
  dma16(wl + boff0 + (KT1) * 32, &sBl[Q][wv * 512]);                              \
  dma16(wl + boff1 + (KT1) * 32, &sBl[Q][wv * 512 + 4096]);                       \
  __builtin_amdgcn_s_barrier();                                                   \
  __builtin_amdgcn_s_setprio(1);                                                  \
  MFMA32(al, bh)                                                                  \
  __builtin_amdgcn_s_setprio(0);                                                  \
  asm volatile("s_waitcnt vmcnt(4)" ::: "memory");                                \
  __builtin_amdgcn_s_barrier();                                                   \
} while (0)

__global__ __launch_bounds__(512, 2) void enc_gemm_fused_kernel(
    const unsigned short* __restrict__ xh, const unsigned short* __restrict__ xl,
    const unsigned short* __restrict__ wh, const unsigned short* __restrict__ wl,
    const float* __restrict__ be, float* __restrict__ z)
{
  __shared__ __align__(16) unsigned short sAh[2][256 * 32];   // 32 KB
  __shared__ __align__(16) unsigned short sAl[2][256 * 32];   // 32 KB
  __shared__ __align__(16) unsigned short sBh[2][256 * 32];   // 32 KB
  __shared__ __align__(16) unsigned short sBl[2][256 * 32];   // 32 KB

  const int tid = threadIdx.x;
  const int lane = tid & 63, wv = tid >> 6;
  const int wm = wv >> 2, wn = wv & 3;          // 2 x 4 wave grid
  const int fr = lane & 15, fq3 = lane >> 4;

  // bijective XCD-chunk swizzle (nwg = 2048, %8 == 0)
  const int bid = blockIdx.x;
  const int sb = (bid & 7) * 256 + (bid >> 3);
  const size_t row0 = (size_t)(sb >> 3) * 256;
  const int col0 = (sb & 7) * 256;

  f32x4 acc[8][4];
#pragma unroll
  for (int i = 0; i < 8; ++i)
#pragma unroll
    for (int j = 0; j < 4; ++j) acc[i][j] = (f32x4){0.f, 0.f, 0.f, 0.f};

  // per-lane invariant stage-source offsets (chunk c: r=c>>2, q=c&3,
  // swizzled q' = q ^ ((r>>1)&3)); chunk set 0: c=tid, set 1: c=tid+512
  const int r0c = tid >> 2, q0c = tid & 3;
  const int qs0 = q0c ^ ((r0c >> 1) & 3);
  const int c1c = tid + 512;
  const int r1c = c1c >> 2, q1c = c1c & 3;
  const int qs1 = q1c ^ ((r1c >> 1) & 3);
  const size_t aoff0 = (row0 + (size_t)r0c) * IN_DIM + qs0 * 8;
  const size_t aoff1 = (row0 + (size_t)r1c) * IN_DIM + qs1 * 8;
  const size_t boff0 = ((size_t)col0 + r0c) * IN_DIM + qs0 * 8;
  const size_t boff1 = ((size_t)col0 + r1c) * IN_DIM + qs1 * 8;

  // prologue: stage all four arrays of tile 0 into parity-0 buffers
  dma16(xh + aoff0, &sAh[0][wv * 512]);
  dma16(xh + aoff1, &sAh[0][wv * 512 + 4096]);
  dma16(wh + boff0, &sBh[0][wv * 512]);
  dma16(wh + boff1, &sBh[0][wv * 512 + 4096]);
  dma16(xl + aoff0, &sAl[0][wv * 512]);
  dma16(xl + aoff1, &sAl[0][wv * 512 + 4096]);
  dma16(wl + boff0, &sBl[0][wv * 512]);
  dma16(wl + boff1, &sBl[0][wv * 512 + 4096]);
  asm volatile("s_waitcnt vmcnt(4)" ::: "memory");   // Ah(0),Bh(0) landed
  __builtin_amdgcn_s_barrier();

  short8 ah[8], al[8], bh[4], bl[4];
  for (int t = 0; t < 16; t += 2) {
    const int k1 = t + 1;
    const int k2 = (t + 2) & 15;     // t=14 -> 0: tail wrap keeps ledger valid
    TILE_BODY(0, 1, k1);
    TILE_BODY(1, 0, k2);
  }

  // epilogue: C/D layout col=lane&15, row=(lane>>4)*4+reg  [m89-verified]
  const int ccol = lane & 15, crow4 = (lane >> 4) * 4;
#pragma unroll
  for (int nt = 0; nt < 4; ++nt) {
    const int col = col0 + wn * 64 + nt * 16 + ccol;
    const float bias = be[col];
#pragma unroll
    for (int mt8 = 0; mt8 < 8; ++mt8) {
      const size_t rb = row0 + wm * 128 + mt8 * 16 + crow4;
#pragma unroll
      for (int r = 0; r < 4; ++r)
        z[(rb + r) * HID + col] = acc[mt8][nt][r] + bias;
    }
  }
}

// ---------------------------------------------------------------------------
// K3: per-row exact-rank threshold + sparsify + decode (fused). Unchanged
// (register-diet selection; bit-identical threshold semantics).
// ---------------------------------------------------------------------------
__global__ __launch_bounds__(256, 4) void topk_decode_kernel(
    float* __restrict__ z, const float* __restrict__ WdT,
    const float* __restrict__ bd, float* __restrict__ recon,
    int* __restrict__ flagCount, int* __restrict__ flagList)
{
  __shared__ float2 s_pair[4][64];
  const int w = threadIdx.x >> 6;
  const int lane = threadIdx.x & 63;
  const int row = blockIdx.x * 4 + w;
  float* zr = z + (size_t)row * HID;

  unsigned u[32];
#pragma unroll
  for (int j2 = 0; j2 < 8; ++j2) {
    const float4 t = *(const float4*)(zr + j2 * 256 + lane * 4);
    u[j2 * 4 + 0] = f2code(t.x);
    u[j2 * 4 + 1] = f2code(t.y);
    u[j2 * 4 + 2] = f2code(t.z);
    u[j2 * 4 + 3] = f2code(t.w);
  }

  // ---- lane max + bitonic sort of the 64 lane-maxima ----
  unsigned lmax = u[0];
#pragma unroll
  for (int j = 1; j < 32; ++j) lmax = u[j] > lmax ? u[j] : lmax;

  unsigned sv = lmax;
#pragma unroll
  for (int k = 2; k <= 64; k <<= 1) {
#pragma unroll
    for (int j = k >> 1; j > 0; j >>= 1) {
      const unsigned other = __shfl_xor(sv, j, 64);
      const bool keepSmall = (((lane & j) == 0) == ((lane & k) == 0));
      const bool less = sv < other;
      sv = (keepSmall == less) ? sv : other;
    }
  }
  // ascending by lane: lane 63 = global max, lane 14 = 50th-largest lane-max
  const unsigned L50  = __shfl(sv, 14, 64);
  const unsigned gmax = __shfl(sv, 63, 64);

  // ---- binary search over multiples of 2^16 (== high-16 search) ----
  unsigned blo = L50 >> 16;          // count(u >= blo<<16) >= 50 guaranteed
  unsigned bhi = (gmax >> 16) + 1u;  // count(u >= bhi<<16) == 0
  while (bhi - blo > 1u) {
    const unsigned mid = blo + ((bhi - blo) >> 1);
    const unsigned m32 = mid << 16;
    int c = 0;
#pragma unroll
    for (int j = 0; j < 32; ++j)
      c += (int)__popcll(__ballot(u[j] >= m32));
    if (c >= TOPK) blo = mid; else bhi = mid;
  }
  const unsigned hs = blo << 16;       // bucket start (T's high half == blo)
  const unsigned he = hs + 0x10000u;   // bucket end (finite floats: no wrap)

  int c_he = 0;
#pragma unroll
  for (int j = 0; j < 32; ++j)
    c_he += (int)__popcll(__ballot(u[j] >= he));
  int r = TOPK - c_he;                 // rank of T inside bucket, >= 1

  // ---- extract r-th largest (with multiplicity) inside [hs, he) ----
  unsigned cur = he;
  while (r > 0) {
    unsigned cand = 0u;
#pragma unroll
    for (int j = 0; j < 32; ++j) {
      const unsigned x = (u[j] >= hs && u[j] < cur) ? u[j] : 0u;
      cand = x > cand ? x : cand;
    }
    cand = wave_max_u(cand);
    int e = 0;
#pragma unroll
    for (int j = 0; j < 32; ++j)
      e += (int)__popcll(__ballot(u[j] == cand));
    r -= e;
    cur = cand;
  }
  const unsigned T = cur;
  const int cT = TOPK - r;             // invariant: count(u >= T) == TOPK - r

  // ---- 51st value (max below T) for the near-tie flag ----
  unsigned below = 0u;
#pragma unroll
  for (int j = 0; j < 32; ++j) {
    const unsigned x = (u[j] < T) ? u[j] : 0u;
    below = x > below ? x : below;
  }
  below = wave_max_u(below);
  if (lane == 0) {
    const float gap = (cT > TOPK) ? 0.0f : (code2f(T) - code2f(below));
    if (gap < MARGIN) {
      const int idx = atomicAdd(flagCount, 1);
      flagList[idx] = row;
    }
  }

  // ---- sparsify in place (code2f(f2code(v)) == v bitwise) ----
#pragma unroll
  for (int j2 = 0; j2 < 8; ++j2) {
    float4 o;
    o.x = (u[j2 * 4 + 0] >= T) ? code2f(u[j2 * 4 + 0]) : 0.0f;
    o.y = (u[j2 * 4 + 1] >= T) ? code2f(u[j2 * 4 + 1]) : 0.0f;
    o.z = (u[j2 * 4 + 2] >= T) ? code2f(u[j2 * 4 + 2]) : 0.0f;
    o.w = (u[j2 * 4 + 3] >= T) ? code2f(u[j2 * 4 + 3]) : 0.0f;
    *(float4*)(zr + j2 * 256 + lane * 4) = o;
  }

  // ---- ballot-compact survivors ----
  s_pair[w][lane] = make_float2(0.0f, __int_as_float(0));
  int base = 0;
#pragma unroll
  for (int j = 0; j < 32; ++j) {
    const bool pass = (u[j] >= T);
    const unsigned long long mask = __ballot(pass);
    if (pass) {
      const int pos = base + __popcll(mask & ((1ull << lane) - 1ull));
      if (pos < 64) {
        const int hidx = (j >> 2) * 256 + lane * 4 + (j & 3);
        s_pair[w][pos] = make_float2(code2f(u[j]), __int_as_float(hidx));
      }
    }
    base += __popcll(mask);
  }
  const int cnt = (base < 64) ? base : 64;

  // ---- decode: acc = b_dec + sum z_i * WdT[h_i], gathers unrolled x2 ----
  float acc[8];
  {
    const float4 b0 = *(const float4*)(bd + lane * 8);
    const float4 b1 = *(const float4*)(bd + lane * 8 + 4);
    acc[0] = b0.x; acc[1] = b0.y; acc[2] = b0.z; acc[3] = b0.w;
    acc[4] = b1.x; acc[5] = b1.y; acc[6] = b1.z; acc[7] = b1.w;
  }
  int i = 0;
  for (; i + 2 <= cnt; i += 2) {
    const float2 p0 = s_pair[w][i];
    const float2 p1 = s_pair[w][i + 1];
    const float* wr0 = WdT + (size_t)__float_as_int(p0.y) * IN_DIM + lane * 8;
    const float* wr1 = WdT + (size_t)__float_as_int(p1.y) * IN_DIM + lane * 8;
    const float4 a0 = *(const float4*)wr0;
    const float4 a1 = *(const float4*)(wr0 + 4);
    const float4 b0 = *(const float4*)wr1;
    const float4 b1 = *(const float4*)(wr1 + 4);
    acc[0] += p0.x * a0.x; acc[1] += p0.x * a0.y;
    acc[2] += p0.x * a0.z; acc[3] += p0.x * a0.w;
    acc[4] += p0.x * a1.x; acc[5] += p0.x * a1.y;
    acc[6] += p0.x * a1.z; acc[7] += p0.x * a1.w;
    acc[0] += p1.x * b0.x; acc[1] += p1.x * b0.y;
    acc[2] += p1.x * b0.z; acc[3] += p1.x * b0.w;
    acc[4] += p1.x * b1.x; acc[5] += p1.x * b1.y;
    acc[6] += p1.x * b1.z; acc[7] += p1.x * b1.w;
  }
  if (i < cnt) {
    const float2 p0 = s_pair[w][i];
    const float* wr0 = WdT + (size_t)__float_as_int(p0.y) * IN_DIM + lane * 8;
    const float4 a0 = *(const float4*)wr0;
    const float4 a1 = *(const float4*)(wr0 + 4);
    acc[0] += p0.x * a0.x; acc[1] += p0.x * a0.y;
    acc[2] += p0.x * a0.z; acc[3] += p0.x * a0.w;
    acc[4] += p0.x * a1.x; acc[5] += p0.x * a1.y;
    acc[6] += p0.x * a1.z; acc[7] += p0.x * a1.w;
  }

  float* rr = recon + (size_t)row * IN_DIM + lane * 8;
  *(float4*)(rr)     = make_float4(acc[0], acc[1], acc[2], acc[3]);
  *(float4*)(rr + 4) = make_float4(acc[4], acc[5], acc[6], acc[7]);
}

// ---------------------------------------------------------------------------
// K4: exact fixup for flagged rows — recompute z with sequential ascending
// fp32 FMA, redo selection, rewrite z_sparse row and recon row. One wave
// per row. Summation order is load-bearing — do not reorder the FMA chain.
// ---------------------------------------------------------------------------
__global__ __launch_bounds__(64) void fixup_kernel(
    const float* __restrict__ x, const float* __restrict__ We,
    const float* __restrict__ be, const float* __restrict__ bd,
    const float* __restrict__ pb, const float* __restrict__ WdT,
    const int* __restrict__ flagCount, const int* __restrict__ flagList,
    float* __restrict__ z, float* __restrict__ recon)
{
  __shared__ float sxc[IN_DIM];
  __shared__ float2 spair[64];
  const int lane = threadIdx.x;
  const int nflag = *flagCount;

  for (int fi = blockIdx.x; fi < nflag; fi += gridDim.x) {
    const int row = flagList[fi];
#pragma unroll
    for (int t = 0; t < 8; ++t) {
      const int k = lane + t * 64;
      sxc[k] = x[(size_t)row * IN_DIM + k] - (bd[k] + pb[k]);
    }
    __syncthreads();

    float v[32];
    unsigned u[32];
#pragma unroll
    for (int j = 0; j < 32; ++j) {
      const int f = lane + 64 * j;
      const float* wr = We + (size_t)f * IN_DIM;
      float a = 0.f;
      for (int k4 = 0; k4 < IN_DIM; k4 += 4) {
        const float4 w4 = *(const float4*)(wr + k4);
        a = fmaf(sxc[k4 + 0], w4.x, a);
        a = fmaf(sxc[k4 + 1], w4.y, a);
        a = fmaf(sxc[k4 + 2], w4.z, a);
        a = fmaf(sxc[k4 + 3], w4.w, a);
      }
      v[j] = a + be[f];
      u[j] = f2code(v[j]);
    }

    unsigned lo = 0u, hi = 0xFFFFFFFFu;
    while (hi - lo > 1u) {
      const unsigned mid = lo + ((hi - lo) >> 1);
      int c = 0;
#pragma unroll
      for (int j = 0; j < 32; ++j) c += (u[j] >= mid) ? 1 : 0;
#pragma unroll
      for (int s = 32; s > 0; s >>= 1) c += __shfl_xor(c, s, 64);
      if (c >= TOPK) lo = mid; else hi = mid;
    }

    // rewrite z_sparse row
#pragma unroll
    for (int j = 0; j < 32; ++j)
      z[(size_t)row * HID + lane + 64 * j] = (u[j] >= lo) ? v[j] : 0.0f;

    // compact + recon
    spair[lane] = make_float2(0.0f, __int_as_float(0));
    __syncthreads();
    int base = 0;
#pragma unroll
    for (int j = 0; j < 32; ++j) {
      const bool pass = (u[j] >= lo);
      const unsigned long long mask = __ballot(pass);
      if (pass) {
        const int pos = base + __popcll(mask & ((1ull << lane) - 1ull));
        if (pos < 64) spair[pos] = make_float2(v[j], __int_as_float(lane + 64 * j));
      }
      base += __popcll(mask);
    }
    __syncthreads();
    const int cnt = (base < 64) ? base : 64;

    float acc[8];
    {
      const float4 b0 = *(const float4*)(bd + lane * 8);
      const float4 b1 = *(const float4*)(bd + lane * 8 + 4);
      acc[0] = b0.x; acc[1] = b0.y; acc[2] = b0.z; acc[3] = b0.w;
      acc[4] = b1.x; acc[5] = b1.y; acc[6] = b1.z; acc[7] = b1.w;
    }
    for (int i = 0; i < cnt; ++i) {
      const float2 p = spair[i];
      const float* wr = WdT + (size_t)__float_as_int(p.y) * IN_DIM + lane * 8;
      const float4 w0 = *(const float4*)wr;
      const float4 w1 = *(const float4*)(wr + 4);
      acc[0] += p.x * w0.x; acc[1] += p.x * w0.y;
      acc[2] += p.x * w0.z; acc[3] += p.x * w0.w;
      acc[4] += p.x * w1.x; acc[5] += p.x * w1.y;
      acc[6] += p.x * w1.z; acc[7] += p.x * w1.w;
    }
    float* rr = recon + (size_t)row * IN_DIM + lane * 8;
    *(float4*)(rr) = make_float4(acc[0], acc[1], acc[2], acc[3]);
    *(float4*)(rr + 4) = make_float4(acc[4], acc[5], acc[6], acc[7]);
    __syncthreads();
  }
}

// ---------------------------------------------------------------------------
extern "C" void kernel_launch(void* const* d_in, const int* in_sizes, int n_in,
                              void* d_out, int out_size, void* d_ws, size_t ws_size,
                              hipStream_t stream)
{
  const float* x  = (const float*)d_in[0];
  const float* We = (const float*)d_in[1];
  const float* be = (const float*)d_in[2];
  const float* Wd = (const float*)d_in[3];
  const float* bd = (const float*)d_in[4];
  const float* pb = (const float*)d_in[5];

  const int M = in_sizes[0] / IN_DIM;   // 65536

  float* recon = (float*)d_out;                        // M x 512
  float* zs    = (float*)d_out + (size_t)M * IN_DIM;   // M x 2048 (z -> z_sparse)
  // xcHi/xcLo live in the recon region (dead until topk_decode writes it)
  unsigned short* xcHi = (unsigned short*)recon;                    // M*512 u16
  unsigned short* xcLo = xcHi + (size_t)M * IN_DIM;                 // M*512 u16

  char* ws = (char*)d_ws;
  float* WdT           = (float*)ws;                    // 4 MB
  unsigned short* WeHi = (unsigned short*)(ws + (4 << 20));   // 2 MB
  unsigned short* WeLo = (unsigned short*)(ws + (6 << 20));   // 2 MB
  int* flagCount       = (int*)(ws + (8 << 20));
  int* flagList        = flagCount + 16;

  hipMemsetAsync(flagCount, 0, 64, stream);
  transpose_wdec_kernel<<<1024, 256, 0, stream>>>(Wd, WdT);
  split_we_kernel<<<(HID * IN_DIM / 4) / 256, 256, 0, stream>>>(We, WeHi, WeLo);
  split_x_kernel<<<(M * (IN_DIM / 4)) / 256, 256, 0, stream>>>(x, bd, pb, xcHi, xcLo);
  enc_gemm_fused_kernel<<<(M / 256) * (HID / 256), 512, 0, stream>>>(
      xcHi, xcLo, WeHi, WeLo, be, zs);
  topk_decode_kernel<<<M / 4, 256, 0, stream>>>(zs, WdT, bd, recon, flagCount, flagList);
  fixup_kernel<<<2048, 64, 0, stream>>>(x, We, be, bd, pb, WdT,
                                        flagCount, flagList, zs, recon);
}

// Round 6
// 1983.509 us; speedup vs baseline: 1.0231x; 1.0231x over previous
//
#include <hip/hip_runtime.h>
#include <cstdint>
#include <cstddef>

#define IN_DIM 512
#define HID 2048
#define TOPK 50
#define MARGIN 4e-5f

typedef __attribute__((ext_vector_type(8))) short short8;
typedef __attribute__((ext_vector_type(4))) float f32x4;

__device__ __forceinline__ unsigned short f2bf(float f) {
  unsigned b = __float_as_uint(f);
  b += 0x7fffu + ((b >> 16) & 1u);          // round-to-nearest-even
  return (unsigned short)(b >> 16);
}
__device__ __forceinline__ float bf2f(unsigned short u) {
  return __uint_as_float(((unsigned)u) << 16);
}
__device__ __forceinline__ unsigned f2code(float f) {
  const unsigned b = __float_as_uint(f);
  return (b & 0x80000000u) ? ~b : (b | 0x80000000u);   // order-preserving
}
__device__ __forceinline__ float code2f(unsigned t) {
  return __uint_as_float((t & 0x80000000u) ? (t & 0x7fffffffu) : ~t);
}
__device__ __forceinline__ void dma16(const void* g, void* l) {
  __builtin_amdgcn_global_load_lds(
      (const __attribute__((address_space(1))) void*)g,
      (__attribute__((address_space(3))) void*)l, 16, 0, 0);
}
__device__ __forceinline__ unsigned wave_max_u(unsigned m) {
#pragma unroll
  for (int s = 32; s > 0; s >>= 1) {
    const unsigned o = __shfl_xor(m, s, 64);
    m = o > m ? o : m;
  }
  return m;
}

// ---------------------------------------------------------------------------
// K0: transpose W_dec (512 x 2048) -> W_dec_T (2048 x 512)
// ---------------------------------------------------------------------------
__global__ __launch_bounds__(256) void transpose_wdec_kernel(
    const float* __restrict__ Wd, float* __restrict__ WdT)
{
  __shared__ float tile[32][33];
  const int bx = blockIdx.x & 63;
  const int by = blockIdx.x >> 6;
  const int tx = threadIdx.x & 31;
  const int ty = threadIdx.x >> 5;
#pragma unroll
  for (int i = 0; i < 4; ++i)
    tile[ty + i * 8][tx] = Wd[(size_t)(by * 32 + ty + i * 8) * HID + bx * 32 + tx];
  __syncthreads();
#pragma unroll
  for (int i = 0; i < 4; ++i)
    WdT[(size_t)(bx * 32 + ty + i * 8) * IN_DIM + by * 32 + tx] = tile[tx][ty + i * 8];
}

// ---------------------------------------------------------------------------
// K1a: split W_enc (2048x512 fp32) -> WeHi, WeLo (bf16 as ushort)
// ---------------------------------------------------------------------------
__global__ __launch_bounds__(256) void split_we_kernel(
    const float* __restrict__ We, unsigned short* __restrict__ wh,
    unsigned short* __restrict__ wl)
{
  const int i4 = blockIdx.x * 256 + threadIdx.x;   // HID*IN_DIM/4 total
  const float4 v = ((const float4*)We)[i4];
  ushort4 h, l;
  h.x = f2bf(v.x); l.x = f2bf(v.x - bf2f(h.x));
  h.y = f2bf(v.y); l.y = f2bf(v.y - bf2f(h.y));
  h.z = f2bf(v.z); l.z = f2bf(v.z - bf2f(h.z));
  h.w = f2bf(v.w); l.w = f2bf(v.w - bf2f(h.w));
  ((ushort4*)wh)[i4] = h;
  ((ushort4*)wl)[i4] = l;
}

// ---------------------------------------------------------------------------
// K1b: xc = x - (b_dec + pre_bias); split -> xcHi, xcLo (stored in recon area)
// ---------------------------------------------------------------------------
__global__ __launch_bounds__(256) void split_x_kernel(
    const float* __restrict__ x, const float* __restrict__ bd,
    const float* __restrict__ pb, unsigned short* __restrict__ xh,
    unsigned short* __restrict__ xl)
{
  const int i4 = blockIdx.x * 256 + threadIdx.x;   // M*IN_DIM/4 total
  const int k4 = (i4 & 127) * 4;
  const float4 v = ((const float4*)x)[i4];
  const float4 b = *(const float4*)(bd + k4);
  const float4 p = *(const float4*)(pb + k4);
  float c0 = v.x - (b.x + p.x);
  float c1 = v.y - (b.y + p.y);
  float c2 = v.z - (b.z + p.z);
  float c3 = v.w - (b.w + p.w);
  ushort4 h, l;
  h.x = f2bf(c0); l.x = f2bf(c0 - bf2f(h.x));
  h.y = f2bf(c1); l.y = f2bf(c1 - bf2f(h.y));
  h.z = f2bf(c2); l.z = f2bf(c2 - bf2f(h.z));
  h.w = f2bf(c3); l.w = f2bf(c3 - bf2f(h.w));
  ((ushort4*)xh)[i4] = h;
  ((ushort4*)xl)[i4] = l;
}

// ---------------------------------------------------------------------------
// K2 (ROUND-5: m201-granule rewrite of the fused bf16x3 GEMM).
// Same math/staging as R4's fragment-fused kernel (ph hh + hl + lh with
// register reuse), but each K32-tile is now SIX 16-MFMA phases (limb x
// m-half quadrants) with <=8 ds_reads + <=2 stage-dma per phase — the fine
// interleave granule m196/m201 proved — and all vmcnt waits guard loads
// issued >=5 phases earlier (vs 1-2 before).
//
// Phase plan per tile t (parity P = t&1, stages -> parity Q = P^1):
//   S1: read ah[0..3],bh[0..3]  (8)  stage Ah(t+1) {2}  MFMA acc[0..3] ah*bh
//   S2: read ah[4..7]           (4)  stage Bh(t+1) {2}  MFMA acc[4..7] ah*bh   vmcnt(6)
//   S3: read al[0..3]           (4)  stage Al(t+1) {2}  MFMA acc[0..3] al*bh
//   S4: read al[4..7]           (4)  stage Bl(t+1) {2}  MFMA acc[4..7] al*bh   vmcnt(8)
//   S5: read bl[0..3]           (4)                     MFMA acc[0..3] ah*bl
//   S6: (no reads)                                      MFMA acc[4..7] ah*bl   vmcnt(4)
// Each phase: {reads | stages} -> s_barrier -> setprio(1) 16xMFMA setprio(0)
//             -> [vmcnt] -> s_barrier.
//
// vmcnt LEDGER (per-wave; 2 dma per stage; tile-periodic, verified):
//   After t-1.S6 vmcnt(4): outstanding = {t-1.S3 Al(t), t-1.S4 Bl(t)}... no:
//   steady state after S6-end vmcnt(4): outstanding 4 = {S3's Al(t+1) 2,
//   S4's Bl(t+1) 2}.  Then t.S1 +2 -> 6, t.S2 +2 -> 8:
//   - t.S2-end vmcnt(6): drains oldest 2 = Al(t+1)?? NO — drains t-1.S3's
//     Al(t) ... ledger in steady state (oldest->newest at t.S2 end):
//     {t-1.S3 Al(t):2, t-1.S4 Bl(t):2, t.S1 Ah(t+1):2, t.S2 Bh(t+1):2}.
//     vmcnt(6) completes Al(t) [issued 5 phases earlier] — read by t.S3. OK
//   - t.S4-end vmcnt(8): outstanding <=6 + S3{2} + S4{2} = 10; completes
//     oldest 2 = Bl(t) [issued 6 phases earlier] — read by t.S5. OK
//   - t.S6-end vmcnt(4): outstanding <=8 = t.S1..S4's stages; completes
//     Ah,Bh(t+1) [issued 5-6 phases earlier] — read by t+1.S1. OK
//   Prologue: stage tile0 in order Ah,Bh,Al,Bl (8 dma) then vmcnt(4)+barrier
//   (Ah,Bh(0) landed; Al(0)/Bl(0) are the oldest pairs drained by t0.S2/S4
//   waits — same ledger as steady state). Tail (t=15) stages wrap to tile 0
//   (garbage, never read) to keep counts valid — do not remove.
// WAR safety: stages into [Q] occur >=4 barriers after [Q]'s last readers.
// ---------------------------------------------------------------------------
__device__ __forceinline__ short8 ldfrag(const unsigned short* h, int row, int fq3) {
  const int qs = fq3 ^ ((row >> 1) & 3);
  return *(const short8*)(h + row * 32 + qs * 8);
}

#define MFMA16(AARR, AOFF, MOFF, BF)                                              \
  _Pragma("unroll")                                                               \
  for (int mt = 0; mt < 4; ++mt)                                                  \
    _Pragma("unroll")                                                             \
    for (int nt = 0; nt < 4; ++nt)                                                \
      acc[(MOFF) + mt][nt] = __builtin_amdgcn_mfma_f32_16x16x32_bf16(             \
          AARR[(AOFF) + mt], BF[nt], acc[(MOFF) + mt][nt], 0, 0, 0);

#define TILE_BODY(P, Q, KT1) do {                                                 \
  /* ---- S1: hh lower ---- */                                                    \
  _Pragma("unroll")                                                               \
  for (int mt = 0; mt < 4; ++mt) ah[mt] = ldfrag(sAh[P], wm * 128 + mt * 16 + fr, fq3);       \
  _Pragma("unroll")                                                               \
  for (int nt = 0; nt < 4; ++nt) bh[nt] = ldfrag(sBh[P], wn * 64 + nt * 16 + fr, fq3);        \
  dma16(xh + aoff0 + (KT1) * 32, &sAh[Q][wv * 512]);                              \
  dma16(xh + aoff1 + (KT1) * 32, &sAh[Q][wv * 512 + 4096]);                       \
  __builtin_amdgcn_s_barrier();                                                   \
  __builtin_amdgcn_s_setprio(1);                                                  \
  MFMA16(ah, 0, 0, bh)                                                            \
  __builtin_amdgcn_s_setprio(0);                                                  \
  __builtin_amdgcn_s_barrier();                                                   \
  /* ---- S2: hh upper ---- */                                                    \
  _Pragma("unroll")                                                               \
  for (int mt = 0; mt < 4; ++mt) ah[4 + mt] = ldfrag(sAh[P], wm * 128 + 64 + mt * 16 + fr, fq3); \
  dma16(wh + boff0 + (KT1) * 32, &sBh[Q][wv * 512]);                              \
  dma16(wh + boff1 + (KT1) * 32, &sBh[Q][wv * 512 + 4096]);                       \
  __builtin_amdgcn_s_barrier();                                                   \
  __builtin_amdgcn_s_setprio(1);                                                  \
  MFMA16(ah, 4, 4, bh)                                                            \
  __builtin_amdgcn_s_setprio(0);                                                  \
  asm volatile("s_waitcnt vmcnt(6)" ::: "memory");                                \
  __builtin_amdgcn_s_barrier();                                                   \
  /* ---- S3: lh lower ---- */                                                    \
  _Pragma("unroll")                                                               \
  for (int mt = 0; mt < 4; ++mt) al[mt] = ldfrag(sAl[P], wm * 128 + mt * 16 + fr, fq3);       \
  dma16(xl + aoff0 + (KT1) * 32, &sAl[Q][wv * 512]);                              \
  dma16(xl + aoff1 + (KT1) * 32, &sAl[Q][wv * 512 + 4096]);                       \
  __builtin_amdgcn_s_barrier();                                                   \
  __builtin_amdgcn_s_setprio(1);                                                  \
  MFMA16(al, 0, 0, bh)                                                            \
  __builtin_amdgcn_s_setprio(0);                                                  \
  __builtin_amdgcn_s_barrier();                                                   \
  /* ---- S4: lh upper ---- */                                                    \
  _Pragma("unroll")                                                               \
  for (int mt = 0; mt < 4; ++mt) al[4 + mt] = ldfrag(sAl[P], wm * 128 + 64 + mt * 16 + fr, fq3); \
  dma16(wl + boff0 + (KT1) * 32, &sBl[Q][wv * 512]);                              \
  dma16(wl + boff1 + (KT1) * 32, &sBl[Q][wv * 512 + 4096]);                       \
  __builtin_amdgcn_s_barrier();                                                   \
  __builtin_amdgcn_s_setprio(1);                                                  \
  MFMA16(al, 4, 4, bh)                                                            \
  __builtin_amdgcn_s_setprio(0);                                                  \
  asm volatile("s_waitcnt vmcnt(8)" ::: "memory");                                \
  __builtin_amdgcn_s_barrier();                                                   \
  /* ---- S5: hl lower (ah reused) ---- */                                        \
  _Pragma("unroll")                                                               \
  for (int nt = 0; nt < 4; ++nt) bl[nt] = ldfrag(sBl[P], wn * 64 + nt * 16 + fr, fq3);        \
  __builtin_amdgcn_s_barrier();                                                   \
  __builtin_amdgcn_s_setprio(1);                                                  \
  MFMA16(ah, 0, 0, bl)                                                            \
  __builtin_amdgcn_s_setprio(0);                                                  \
  __builtin_amdgcn_s_barrier();                                                   \
  /* ---- S6: hl upper (no reads) ---- */                                         \
  __builtin_amdgcn_s_barrier();                                                   \
  __builtin_amdgcn_s_setprio(1);                                                  \
  MFMA16(ah, 4, 4, bl)                                                            \
  __builtin_amdgcn_s_setprio(0);                                                  \
  asm volatile("s_waitcnt vmcnt(4)" ::: "memory");                                \
  __builtin_amdgcn_s_barrier();                                                   \
} while (0)

__global__ __launch_bounds__(512, 2) void enc_gemm_fused_kernel(
    const unsigned short* __restrict__ xh, const unsigned short* __restrict__ xl,
    const unsigned short* __restrict__ wh, const unsigned short* __restrict__ wl,
    const float* __restrict__ be, float* __restrict__ z)
{
  __shared__ __align__(16) unsigned short sAh[2][256 * 32];   // 32 KB
  __shared__ __align__(16) unsigned short sAl[2][256 * 32];   // 32 KB
  __shared__ __align__(16) unsigned short sBh[2][256 * 32];   // 32 KB
  __shared__ __align__(16) unsigned short sBl[2][256 * 32];   // 32 KB

  const int tid = threadIdx.x;
  const int lane = tid & 63, wv = tid >> 6;
  const int wm = wv >> 2, wn = wv & 3;          // 2 x 4 wave grid
  const int fr = lane & 15, fq3 = lane >> 4;

  // bijective XCD-chunk swizzle (nwg = 2048, %8 == 0)
  const int bid = blockIdx.x;
  const int sb = (bid & 7) * 256 + (bid >> 3);
  const size_t row0 = (size_t)(sb >> 3) * 256;
  const int col0 = (sb & 7) * 256;

  f32x4 acc[8][4];
#pragma unroll
  for (int i = 0; i < 8; ++i)
#pragma unroll
    for (int j = 0; j < 4; ++j) acc[i][j] = (f32x4){0.f, 0.f, 0.f, 0.f};

  // per-lane invariant stage-source offsets (chunk c: r=c>>2, q=c&3,
  // swizzled q' = q ^ ((r>>1)&3)); chunk set 0: c=tid, set 1: c=tid+512
  const int r0c = tid >> 2, q0c = tid & 3;
  const int qs0 = q0c ^ ((r0c >> 1) & 3);
  const int c1c = tid + 512;
  const int r1c = c1c >> 2, q1c = c1c & 3;
  const int qs1 = q1c ^ ((r1c >> 1) & 3);
  const size_t aoff0 = (row0 + (size_t)r0c) * IN_DIM + qs0 * 8;
  const size_t aoff1 = (row0 + (size_t)r1c) * IN_DIM + qs1 * 8;
  const size_t boff0 = ((size_t)col0 + r0c) * IN_DIM + qs0 * 8;
  const size_t boff1 = ((size_t)col0 + r1c) * IN_DIM + qs1 * 8;

  // prologue: stage tile 0 in ledger order Ah, Bh, Al, Bl
  dma16(xh + aoff0, &sAh[0][wv * 512]);
  dma16(xh + aoff1, &sAh[0][wv * 512 + 4096]);
  dma16(wh + boff0, &sBh[0][wv * 512]);
  dma16(wh + boff1, &sBh[0][wv * 512 + 4096]);
  dma16(xl + aoff0, &sAl[0][wv * 512]);
  dma16(xl + aoff1, &sAl[0][wv * 512 + 4096]);
  dma16(wl + boff0, &sBl[0][wv * 512]);
  dma16(wl + boff1, &sBl[0][wv * 512 + 4096]);
  asm volatile("s_waitcnt vmcnt(4)" ::: "memory");   // Ah(0),Bh(0) landed
  __builtin_amdgcn_s_barrier();

  short8 ah[8], al[8], bh[4], bl[4];
  for (int t = 0; t < 16; t += 2) {
    const int k1 = t + 1;
    const int k2 = (t + 2) & 15;     // t=14 -> 0: tail wrap keeps ledger valid
    TILE_BODY(0, 1, k1);
    TILE_BODY(1, 0, k2);
  }

  // epilogue: C/D layout col=lane&15, row=(lane>>4)*4+reg  [m89-verified]
  const int ccol = lane & 15, crow4 = (lane >> 4) * 4;
#pragma unroll
  for (int nt = 0; nt < 4; ++nt) {
    const int col = col0 + wn * 64 + nt * 16 + ccol;
    const float bias = be[col];
#pragma unroll
    for (int mt8 = 0; mt8 < 8; ++mt8) {
      const size_t rb = row0 + wm * 128 + mt8 * 16 + crow4;
#pragma unroll
      for (int r = 0; r < 4; ++r)
        z[(rb + r) * HID + col] = acc[mt8][nt][r] + bias;
    }
  }
}

// ---------------------------------------------------------------------------
// K3: per-row exact-rank threshold + sparsify + decode (fused). Unchanged
// (register-diet selection; bit-identical threshold semantics).
// ---------------------------------------------------------------------------
__global__ __launch_bounds__(256, 4) void topk_decode_kernel(
    float* __restrict__ z, const float* __restrict__ WdT,
    const float* __restrict__ bd, float* __restrict__ recon,
    int* __restrict__ flagCount, int* __restrict__ flagList)
{
  __shared__ float2 s_pair[4][64];
  const int w = threadIdx.x >> 6;
  const int lane = threadIdx.x & 63;
  const int row = blockIdx.x * 4 + w;
  float* zr = z + (size_t)row * HID;

  unsigned u[32];
#pragma unroll
  for (int j2 = 0; j2 < 8; ++j2) {
    const float4 t = *(const float4*)(zr + j2 * 256 + lane * 4);
    u[j2 * 4 + 0] = f2code(t.x);
    u[j2 * 4 + 1] = f2code(t.y);
    u[j2 * 4 + 2] = f2code(t.z);
    u[j2 * 4 + 3] = f2code(t.w);
  }

  // ---- lane max + bitonic sort of the 64 lane-maxima ----
  unsigned lmax = u[0];
#pragma unroll
  for (int j = 1; j < 32; ++j) lmax = u[j] > lmax ? u[j] : lmax;

  unsigned sv = lmax;
#pragma unroll
  for (int k = 2; k <= 64; k <<= 1) {
#pragma unroll
    for (int j = k >> 1; j > 0; j >>= 1) {
      const unsigned other = __shfl_xor(sv, j, 64);
      const bool keepSmall = (((lane & j) == 0) == ((lane & k) == 0));
      const bool less = sv < other;
      sv = (keepSmall == less) ? sv : other;
    }
  }
  // ascending by lane: lane 63 = global max, lane 14 = 50th-largest lane-max
  const unsigned L50  = __shfl(sv, 14, 64);
  const unsigned gmax = __shfl(sv, 63, 64);

  // ---- binary search over multiples of 2^16 (== high-16 search) ----
  unsigned blo = L50 >> 16;          // count(u >= blo<<16) >= 50 guaranteed
  unsigned bhi = (gmax >> 16) + 1u;  // count(u >= bhi<<16) == 0
  while (bhi - blo > 1u) {
    const unsigned mid = blo + ((bhi - blo) >> 1);
    const unsigned m32 = mid << 16;
    int c = 0;
#pragma unroll
    for (int j = 0; j < 32; ++j)
      c += (int)__popcll(__ballot(u[j] >= m32));
    if (c >= TOPK) blo = mid; else bhi = mid;
  }
  const unsigned hs = blo << 16;       // bucket start (T's high half == blo)
  const unsigned he = hs + 0x10000u;   // bucket end (finite floats: no wrap)

  int c_he = 0;
#pragma unroll
  for (int j = 0; j < 32; ++j)
    c_he += (int)__popcll(__ballot(u[j] >= he));
  int r = TOPK - c_he;                 // rank of T inside bucket, >= 1

  // ---- extract r-th largest (with multiplicity) inside [hs, he) ----
  unsigned cur = he;
  while (r > 0) {
    unsigned cand = 0u;
#pragma unroll
    for (int j = 0; j < 32; ++j) {
      const unsigned x = (u[j] >= hs && u[j] < cur) ? u[j] : 0u;
      cand = x > cand ? x : cand;
    }
    cand = wave_max_u(cand);
    int e = 0;
#pragma unroll
    for (int j = 0; j < 32; ++j)
      e += (int)__popcll(__ballot(u[j] == cand));
    r -= e;
    cur = cand;
  }
  const unsigned T = cur;
  const int cT = TOPK - r;             // invariant: count(u >= T) == TOPK - r

  // ---- 51st value (max below T) for the near-tie flag ----
  unsigned below = 0u;
#pragma unroll
  for (int j = 0; j < 32; ++j) {
    const unsigned x = (u[j] < T) ? u[j] : 0u;
    below = x > below ? x : below;
  }
  below = wave_max_u(below);
  if (lane == 0) {
    const float gap = (cT > TOPK) ? 0.0f : (code2f(T) - code2f(below));
    if (gap < MARGIN) {
      const int idx = atomicAdd(flagCount, 1);
      flagList[idx] = row;
    }
  }

  // ---- sparsify in place (code2f(f2code(v)) == v bitwise) ----
#pragma unroll
  for (int j2 = 0; j2 < 8; ++j2) {
    float4 o;
    o.x = (u[j2 * 4 + 0] >= T) ? code2f(u[j2 * 4 + 0]) : 0.0f;
    o.y = (u[j2 * 4 + 1] >= T) ? code2f(u[j2 * 4 + 1]) : 0.0f;
    o.z = (u[j2 * 4 + 2] >= T) ? code2f(u[j2 * 4 + 2]) : 0.0f;
    o.w = (u[j2 * 4 + 3] >= T) ? code2f(u[j2 * 4 + 3]) : 0.0f;
    *(float4*)(zr + j2 * 256 + lane * 4) = o;
  }

  // ---- ballot-compact survivors ----
  s_pair[w][lane] = make_float2(0.0f, __int_as_float(0));
  int base = 0;
#pragma unroll
  for (int j = 0; j < 32; ++j) {
    const bool pass = (u[j] >= T);
    const unsigned long long mask = __ballot(pass);
    if (pass) {
      const int pos = base + __popcll(mask & ((1ull << lane) - 1ull));
      if (pos < 64) {
        const int hidx = (j >> 2) * 256 + lane * 4 + (j & 3);
        s_pair[w][pos] = make_float2(code2f(u[j]), __int_as_float(hidx));
      }
    }
    base += __popcll(mask);
  }
  const int cnt = (base < 64) ? base : 64;

  // ---- decode: acc = b_dec + sum z_i * WdT[h_i], gathers unrolled x2 ----
  float acc[8];
  {
    const float4 b0 = *(const float4*)(bd + lane * 8);
    const float4 b1 = *(const float4*)(bd + lane * 8 + 4);
    acc[0] = b0.x; acc[1] = b0.y; acc[2] = b0.z; acc[3] = b0.w;
    acc[4] = b1.x; acc[5] = b1.y; acc[6] = b1.z; acc[7] = b1.w;
  }
  int i = 0;
  for (; i + 2 <= cnt; i += 2) {
    const float2 p0 = s_pair[w][i];
    const float2 p1 = s_pair[w][i + 1];
    const float* wr0 = WdT + (size_t)__float_as_int(p0.y) * IN_DIM + lane * 8;
    const float* wr1 = WdT + (size_t)__float_as_int(p1.y) * IN_DIM + lane * 8;
    const float4 a0 = *(const float4*)wr0;
    const float4 a1 = *(const float4*)(wr0 + 4);
    const float4 b0 = *(const float4*)wr1;
    const float4 b1 = *(const float4*)(wr1 + 4);
    acc[0] += p0.x * a0.x; acc[1] += p0.x * a0.y;
    acc[2] += p0.x * a0.z; acc[3] += p0.x * a0.w;
    acc[4] += p0.x * a1.x; acc[5] += p0.x * a1.y;
    acc[6] += p0.x * a1.z; acc[7] += p0.x * a1.w;
    acc[0] += p1.x * b0.x; acc[1] += p1.x * b0.y;
    acc[2] += p1.x * b0.z; acc[3] += p1.x * b0.w;
    acc[4] += p1.x * b1.x; acc[5] += p1.x * b1.y;
    acc[6] += p1.x * b1.z; acc[7] += p1.x * b1.w;
  }
  if (i < cnt) {
    const float2 p0 = s_pair[w][i];
    const float* wr0 = WdT + (size_t)__float_as_int(p0.y) * IN_DIM + lane * 8;
    const float4 a0 = *(const float4*)wr0;
    const float4 a1 = *(const float4*)(wr0 + 4);
    acc[0] += p0.x * a0.x; acc[1] += p0.x * a0.y;
    acc[2] += p0.x * a0.z; acc[3] += p0.x * a0.w;
    acc[4] += p0.x * a1.x; acc[5] += p0.x * a1.y;
    acc[6] += p0.x * a1.z; acc[7] += p0.x * a1.w;
  }

  float* rr = recon + (size_t)row * IN_DIM + lane * 8;
  *(float4*)(rr)     = make_float4(acc[0], acc[1], acc[2], acc[3]);
  *(float4*)(rr + 4) = make_float4(acc[4], acc[5], acc[6], acc[7]);
}

// ---------------------------------------------------------------------------
// K4: exact fixup for flagged rows — recompute z with sequential ascending
// fp32 FMA, redo selection, rewrite z_sparse row and recon row. One wave
// per row. Summation order is load-bearing — do not reorder the FMA chain.
// ---------------------------------------------------------------------------
__global__ __launch_bounds__(64) void fixup_kernel(
    const float* __restrict__ x, const float* __restrict__ We,
    const float* __restrict__ be, const float* __restrict__ bd,
    const float* __restrict__ pb, const float* __restrict__ WdT,
    const int* __restrict__ flagCount, const int* __restrict__ flagList,
    float* __restrict__ z, float* __restrict__ recon)
{
  __shared__ float sxc[IN_DIM];
  __shared__ float2 spair[64];
  const int lane = threadIdx.x;
  const int nflag = *flagCount;

  for (int fi = blockIdx.x; fi < nflag; fi += gridDim.x) {
    const int row = flagList[fi];
#pragma unroll
    for (int t = 0; t < 8; ++t) {
      const int k = lane + t * 64;
      sxc[k] = x[(size_t)row * IN_DIM + k] - (bd[k] + pb[k]);
    }
    __syncthreads();

    float v[32];
    unsigned u[32];
#pragma unroll
    for (int j = 0; j < 32; ++j) {
      const int f = lane + 64 * j;
      const float* wr = We + (size_t)f * IN_DIM;
      float a = 0.f;
      for (int k4 = 0; k4 < IN_DIM; k4 += 4) {
        const float4 w4 = *(const float4*)(wr + k4);
        a = fmaf(sxc[k4 + 0], w4.x, a);
        a = fmaf(sxc[k4 + 1], w4.y, a);
        a = fmaf(sxc[k4 + 2], w4.z, a);
        a = fmaf(sxc[k4 + 3], w4.w, a);
      }
      v[j] = a + be[f];
      u[j] = f2code(v[j]);
    }

    unsigned lo = 0u, hi = 0xFFFFFFFFu;
    while (hi - lo > 1u) {
      const unsigned mid = lo + ((hi - lo) >> 1);
      int c = 0;
#pragma unroll
      for (int j = 0; j < 32; ++j) c += (u[j] >= mid) ? 1 : 0;
#pragma unroll
      for (int s = 32; s > 0; s >>= 1) c += __shfl_xor(c, s, 64);
      if (c >= TOPK) lo = mid; else hi = mid;
    }

    // rewrite z_sparse row
#pragma unroll
    for (int j = 0; j < 32; ++j)
      z[(size_t)row * HID + lane + 64 * j] = (u[j] >= lo) ? v[j] : 0.0f;

    // compact + recon
    spair[lane] = make_float2(0.0f, __int_as_float(0));
    __syncthreads();
    int base = 0;
#pragma unroll
    for (int j = 0; j < 32; ++j) {
      const bool pass = (u[j] >= lo);
      const unsigned long long mask = __ballot(pass);
      if (pass) {
        const int pos = base + __popcll(mask & ((1ull << lane) - 1ull));
        if (pos < 64) spair[pos] = make_float2(v[j], __int_as_float(lane + 64 * j));
      }
      base += __popcll(mask);
    }
    __syncthreads();
    const int cnt = (base < 64) ? base : 64;

    float acc[8];
    {
      const float4 b0 = *(const float4*)(bd + lane * 8);
      const float4 b1 = *(const float4*)(bd + lane * 8 + 4);
      acc[0] = b0.x; acc[1] = b0.y; acc[2] = b0.z; acc[3] = b0.w;
      acc[4] = b1.x; acc[5] = b1.y; acc[6] = b1.z; acc[7] = b1.w;
    }
    for (int i = 0; i < cnt; ++i) {
      const float2 p = spair[i];
      const float* wr = WdT + (size_t)__float_as_int(p.y) * IN_DIM + lane * 8;
      const float4 w0 = *(const float4*)wr;
      const float4 w1 = *(const float4*)(wr + 4);
      acc[0] += p.x * w0.x; acc[1] += p.x * w0.y;
      acc[2] += p.x * w0.z; acc[3] += p.x * w0.w;
      acc[4] += p.x * w1.x; acc[5] += p.x * w1.y;
      acc[6] += p.x * w1.z; acc[7] += p.x * w1.w;
    }
    float* rr = recon + (size_t)row * IN_DIM + lane * 8;
    *(float4*)(rr) = make_float4(acc[0], acc[1], acc[2], acc[3]);
    *(float4*)(rr + 4) = make_float4(acc[4], acc[5], acc[6], acc[7]);
    __syncthreads();
  }
}

// ---------------------------------------------------------------------------
extern "C" void kernel_launch(void* const* d_in, const int* in_sizes, int n_in,
                              void* d_out, int out_size, void* d_ws, size_t ws_size,
                              hipStream_t stream)
{
  const float* x  = (const float*)d_in[0];
  const float* We = (const float*)d_in[1];
  const float* be = (const float*)d_in[2];
  const float* Wd = (const float*)d_in[3];
  const float* bd = (const float*)d_in[4];
  const float* pb = (const float*)d_in[5];

  const int M = in_sizes[0] / IN_DIM;   // 65536

  float* recon = (float*)d_out;                        // M x 512
  float* zs    = (float*)d_out + (size_t)M * IN_DIM;   // M x 2048 (z -> z_sparse)
  // xcHi/xcLo live in the recon region (dead until topk_decode writes it)
  unsigned short* xcHi = (unsigned short*)recon;                    // M*512 u16
  unsigned short* xcLo = xcHi + (size_t)M * IN_DIM;                 // M*512 u16

  char* ws = (char*)d_ws;
  float* WdT           = (float*)ws;                    // 4 MB
  unsigned short* WeHi = (unsigned short*)(ws + (4 << 20));   // 2 MB
  unsigned short* WeLo = (unsigned short*)(ws + (6 << 20));   // 2 MB
  int* flagCount       = (int*)(ws + (8 << 20));
  int* flagList        = flagCount + 16;

  hipMemsetAsync(flagCount, 0, 64, stream);
  transpose_wdec_kernel<<<1024, 256, 0, stream>>>(Wd, WdT);
  split_we_kernel<<<(HID * IN_DIM / 4) / 256, 256, 0, stream>>>(We, WeHi, WeLo);
  split_x_kernel<<<(M * (IN_DIM / 4)) / 256, 256, 0, stream>>>(x, bd, pb, xcHi, xcLo);
  enc_gemm_fused_kernel<<<(M / 256) * (HID / 256), 512, 0, stream>>>(
      xcHi, xcLo, WeHi, WeLo, be, zs);
  topk_decode_kernel<<<M / 4, 256, 0, stream>>>(zs, WdT, bd, recon, flagCount, flagList);
  fixup_kernel<<<2048, 64, 0, stream>>>(x, We, be, bd, pb, WdT,
                                        flagCount, flagList, zs, recon);
}